// Round 3
// baseline (220.940 us; speedup 1.0000x reference)
//
#include <hip/hip_runtime.h>
#include <math.h>
#include <stdint.h>

// Problem constants (static per reference)
#define BB 8
#define NN 384
#define FF 64
#define TT 192
#define NSRC 383          // T + TAU - 1
#define NSINK 192
#define SS 5
#define NEDGE 441600      // B * 55200
#define BN (BB * NN)      // 3072
#define NTHREADS (NEDGE / 2)      // 220800, 2 edges per thread
#define NBLK ((NTHREADS + 255) / 256)  // 863
#define TOTTHR (NBLK * 256)       // 220928
#define OUTV ((BB * NN * NN) / 4) // 294912 float4 to zero

#define CONST_AS __attribute__((address_space(4)))
typedef const CONST_AS float cfloat;

// ---------------- prep: transposed node projections + weight folding ----------------
// blocks 0..BN-1: At[k][bn] = (nodes[bn] @ w1_top)[k] + b1[k]
//                 Bt[k][bn] = (nodes[bn] @ w1_bot)[k]
// block BN: W2kj[k][j] = g1[k]*w2[k][j]   (k-major, j contiguous)
//           wcol[j] = sum_k W2kj[k][j]
//           cb[j]   = b2[j] + sum_k be1[k]*w2[k][j]
//           gw[j]   = g2[j]*w3[j];  cwsgw = {b3 + sum_j be2[j]*w3[j], sum_j gw[j]}
__global__ __launch_bounds__(64) void prep_all(
    const float* __restrict__ nodes, const float* __restrict__ w1,
    const float* __restrict__ b1,
    const float* __restrict__ w2, const float* __restrict__ b2,
    const float* __restrict__ g1, const float* __restrict__ be1,
    const float* __restrict__ g2, const float* __restrict__ be2,
    const float* __restrict__ w3, const float* __restrict__ b3,
    float* __restrict__ At, float* __restrict__ Bt,
    float* __restrict__ W2kj, float* __restrict__ wcol,
    float* __restrict__ cb, float* __restrict__ gw,
    float* __restrict__ cwsgw) {
  const int bn = blockIdx.x;
  if (bn < BN) {
    const int k = threadIdx.x;
    __shared__ float nd[FF];
    nd[k] = nodes[bn * FF + k];
    __syncthreads();
    float a = b1[k];
    float bb = 0.f;
#pragma unroll
    for (int f = 0; f < FF; ++f) {
      a  = fmaf(nd[f], w1[f * FF + k], a);
      bb = fmaf(nd[f], w1[(FF + f) * FF + k], bb);
    }
    At[k * BN + bn] = a;
    Bt[k * BN + bn] = bb;
  } else {
    const int j = threadIdx.x;
    float cbj = b2[j];
    float wc = 0.f;
    for (int k = 0; k < FF; ++k) {
      const float wraw = w2[k * FF + j];
      const float w = g1[k] * wraw;
      W2kj[k * FF + j] = w;
      wc += w;
      cbj = fmaf(be1[k], wraw, cbj);
    }
    wcol[j] = wc;
    cb[j] = cbj;
    const float gwj = g2[j] * w3[j];
    gw[j] = gwj;
    __shared__ float sA[FF], sB[FF];
    sA[j] = gwj;
    sB[j] = be2[j] * w3[j];
    __syncthreads();
    if (j == 0) {
      float a = 0.f, bq = 0.f;
      for (int i = 0; i < FF; ++i) { a += sA[i]; bq += sB[i]; }
      cwsgw[0] = b3[0] + bq;
      cwsgw[1] = a;
    }
  }
}

// ---------------- main: zero out + per-edge MLP (2 edges/thread) ----------------
__global__ __launch_bounds__(256, 3) void edge_mlp(
    const float* __restrict__ At, const float* __restrict__ Bt,
    const float* __restrict__ W2kjg, const float* __restrict__ wcolg,
    const float* __restrict__ cbg, const float* __restrict__ gwg,
    const float* __restrict__ cwsgwg,
    const int* __restrict__ bidx, const int* __restrict__ ridx,
    const int* __restrict__ cidx, float* __restrict__ L,
    float4* __restrict__ outv) {
  const int tid = blockIdx.x * 256 + threadIdx.x;

  // fused zeroing of the output grid
  for (int i = tid; i < OUTV; i += TOTTHR)
    outv[i] = make_float4(0.f, 0.f, 0.f, 0.f);
  if (tid >= NTHREADS) return;

  // constant-AS views: uniform-address reads -> s_load
  cfloat* W2kj = (cfloat*)(uintptr_t)W2kjg;
  cfloat* wcol = (cfloat*)(uintptr_t)wcolg;
  cfloat* cb = (cfloat*)(uintptr_t)cbg;
  cfloat* gw = (cfloat*)(uintptr_t)gwg;
  cfloat* cwsgw = (cfloat*)(uintptr_t)cwsgwg;

  const int e0 = 2 * tid, e1 = 2 * tid + 1;
  const int b0 = bidx[e0], r0 = ridx[e0], c0 = cidx[e0];
  const int b1 = bidx[e1], r1 = ridx[e1], c1 = cidx[e1];
  const int offA0 = b0 * NN + r0, offB0 = b0 * NN + c0;
  const int offA1 = b1 * NN + r1, offB1 = b1 * NN + c1;

  // per-edge running stats of x = relu(a+b) over all k
  float sA0 = 0.f, sQ0 = 0.f, sA1 = 0.f, sQ1 = 0.f;
  float s1_0 = 0.f, s2_0 = 0.f, s3_0 = 0.f;
  float s1_1 = 0.f, s2_1 = 0.f, s3_1 = 0.f;
  float mu1 = 0.f, rstd1 = 0.f;

  // ---------------- pass A: j in [0,32), also accumulate layer-1 stats ----------------
  {
    float t0[32], t1[32];
#pragma unroll
    for (int j = 0; j < 32; ++j) { t0[j] = 0.f; t1[j] = 0.f; }
    const float* pA = At;
    const float* pB = Bt;
#pragma unroll 4
    for (int k = 0; k < FF; ++k) {
      const float a0 = pA[offA0], a1 = pA[offA1];
      const float bv0 = pB[offB0], bv1 = pB[offB1];
      pA += BN; pB += BN;
      const float x0 = fmaxf(a0 + bv0, 0.f);
      const float x1 = fmaxf(a1 + bv1, 0.f);
      sA0 += x0; sQ0 = fmaf(x0, x0, sQ0);
      sA1 += x1; sQ1 = fmaf(x1, x1, sQ1);
      cfloat* Wk = W2kj + k * FF;
#pragma unroll
      for (int j = 0; j < 32; ++j) {
        const float w = Wk[j];
        t0[j] = fmaf(x0, w, t0[j]);
        t1[j] = fmaf(x1, w, t1[j]);
      }
    }
    mu1 = (sA0 /*dummy keep*/, sA0) * 0.f;  // placeholder overwritten below (keeps scope)
    mu1 = sA0 * (1.f / FF);
    const float var0 = sQ0 * (1.f / FF) - mu1 * mu1;
    // NOTE: stats are per-edge; compute both edges' LN params
    const float mu1_0 = mu1;
    const float rstd1_0 = 1.f / sqrtf(var0 + 1e-5f);
    const float mu1_1 = sA1 * (1.f / FF);
    const float var1v = sQ1 * (1.f / FF) - mu1_1 * mu1_1;
    const float rstd1_1 = 1.f / sqrtf(var1v + 1e-5f);
    mu1 = mu1_0; rstd1 = rstd1_0;   // stash edge0 in the outer vars
    // reuse sA1/sQ1 slots to carry edge1 LN params to pass B
    sA1 = mu1_1; sQ1 = rstd1_1;
#pragma unroll
    for (int j = 0; j < 32; ++j) {
      const float wcj = wcol[j], cbj = cb[j], gwj = gw[j];
      const float pre0 = fmaf(rstd1_0, fmaf(-mu1_0, wcj, t0[j]), cbj);
      const float tr0 = fmaxf(pre0, 0.f);
      s1_0 += tr0; s2_0 = fmaf(tr0, tr0, s2_0); s3_0 = fmaf(tr0, gwj, s3_0);
      const float pre1 = fmaf(rstd1_1, fmaf(-mu1_1, wcj, t1[j]), cbj);
      const float tr1 = fmaxf(pre1, 0.f);
      s1_1 += tr1; s2_1 = fmaf(tr1, tr1, s2_1); s3_1 = fmaf(tr1, gwj, s3_1);
    }
  }

  // ---------------- pass B: j in [32,64) ----------------
  {
    const float mu1_0 = mu1, rstd1_0 = rstd1;
    const float mu1_1 = sA1, rstd1_1 = sQ1;
    float t0[32], t1[32];
#pragma unroll
    for (int j = 0; j < 32; ++j) { t0[j] = 0.f; t1[j] = 0.f; }
    const float* pA = At;
    const float* pB = Bt;
#pragma unroll 4
    for (int k = 0; k < FF; ++k) {
      const float a0 = pA[offA0], a1 = pA[offA1];
      const float bv0 = pB[offB0], bv1 = pB[offB1];
      pA += BN; pB += BN;
      const float x0 = fmaxf(a0 + bv0, 0.f);
      const float x1 = fmaxf(a1 + bv1, 0.f);
      cfloat* Wk = W2kj + k * FF + 32;
#pragma unroll
      for (int j = 0; j < 32; ++j) {
        const float w = Wk[j];
        t0[j] = fmaf(x0, w, t0[j]);
        t1[j] = fmaf(x1, w, t1[j]);
      }
    }
#pragma unroll
    for (int j = 0; j < 32; ++j) {
      const float wcj = wcol[32 + j], cbj = cb[32 + j], gwj = gw[32 + j];
      const float pre0 = fmaf(rstd1_0, fmaf(-mu1_0, wcj, t0[j]), cbj);
      const float tr0 = fmaxf(pre0, 0.f);
      s1_0 += tr0; s2_0 = fmaf(tr0, tr0, s2_0); s3_0 = fmaf(tr0, gwj, s3_0);
      const float pre1 = fmaf(rstd1_1, fmaf(-mu1_1, wcj, t1[j]), cbj);
      const float tr1 = fmaxf(pre1, 0.f);
      s1_1 += tr1; s2_1 = fmaf(tr1, tr1, s2_1); s3_1 = fmaf(tr1, gwj, s3_1);
    }
  }

  // ---------------- layer-3 epilogue per edge ----------------
  const float cw = cwsgw[0], sgw = cwsgw[1];
  {
    const float mu2 = s1_0 * (1.f / FF);
    const float var2 = s2_0 * (1.f / FF) - mu2 * mu2;
    const float rstd2 = 1.f / sqrtf(var2 + 1e-5f);
    const float logit = fmaf(rstd2, fmaf(-mu2, sgw, s3_0), cw);
    L[(b0 * NSINK + (r0 - TT)) * NSRC + c0] = logit;
  }
  {
    const float mu2 = s1_1 * (1.f / FF);
    const float var2 = s2_1 * (1.f / FF) - mu2 * mu2;
    const float rstd2 = 1.f / sqrtf(var2 + 1e-5f);
    const float logit = fmaf(rstd2, fmaf(-mu2, sgw, s3_1), cw);
    L[(b1 * NSINK + (r1 - TT)) * NSRC + c1] = logit;
  }
}

// ---------------- argmax over sources + scatter ones ----------------
__global__ __launch_bounds__(256) void argmax_scatter(
    const float* __restrict__ L, const float* __restrict__ gum,
    float* __restrict__ out) {
  const int task = blockIdx.x * 4 + (threadIdx.x >> 6);  // ((s*B+b)*192+row)
  const int lane = threadIdx.x & 63;
  const int row = task % NSINK;
  const int sb = task / NSINK;   // s*B + b
  const int b = sb & 7;
  const int r = row + TT;

  const float* __restrict__ lrow = L + (b * NSINK + row) * NSRC;
  const float* __restrict__ grow = gum + task * NSRC;

  float bv = -INFINITY;
  int bi = 0;
  for (int c = lane; c < r; c += 64) {
    const float v = lrow[c] + grow[c];
    if (v > bv) { bv = v; bi = c; }   // strict > keeps smallest index per lane
  }
#pragma unroll
  for (int off = 32; off > 0; off >>= 1) {
    const float ov = __shfl_xor(bv, off, 64);
    const int oi = __shfl_xor(bi, off, 64);
    if (ov > bv || (ov == bv && oi < bi)) { bv = ov; bi = oi; }
  }
  if (lane == 0) out[(b * NN + r) * NN + bi] = 1.0f;
}

extern "C" void kernel_launch(void* const* d_in, const int* in_sizes, int n_in,
                              void* d_out, int out_size, void* d_ws, size_t ws_size,
                              hipStream_t stream) {
  const float* nodes = (const float*)d_in[0];
  const float* w1 = (const float*)d_in[1];
  const float* b1 = (const float*)d_in[2];
  const float* g1 = (const float*)d_in[3];
  const float* be1 = (const float*)d_in[4];
  const float* w2 = (const float*)d_in[5];
  const float* b2 = (const float*)d_in[6];
  const float* g2 = (const float*)d_in[7];
  const float* be2 = (const float*)d_in[8];
  const float* w3 = (const float*)d_in[9];
  const float* b3 = (const float*)d_in[10];
  const float* gum = (const float*)d_in[11];
  const int* bidx = (const int*)d_in[12];
  const int* ridx = (const int*)d_in[13];
  const int* cidx = (const int*)d_in[14];
  float* out = (float*)d_out;

  // workspace layout (floats)
  float* ws = (float*)d_ws;
  float* At = ws;                      // 64*3072 = 196608
  float* Bt = At + FF * BN;            // 196608
  float* W2kj = Bt + FF * BN;          // 4096
  float* wcol = W2kj + FF * FF;        // 64
  float* cb = wcol + FF;               // 64
  float* gw = cb + FF;                 // 64
  float* cwsgw = gw + FF;              // 2
  float* L = ws + 397520;              // 8*192*383 = 588288, aligned
  (void)ws_size; (void)n_in; (void)in_sizes; (void)out_size;

  hipLaunchKernelGGL(prep_all, dim3(BN + 1), dim3(64), 0, stream,
                     nodes, w1, b1, w2, b2, g1, be1, g2, be2, w3, b3,
                     At, Bt, W2kj, wcol, cb, gw, cwsgw);
  hipLaunchKernelGGL(edge_mlp, dim3(NBLK), dim3(256), 0, stream,
                     At, Bt, W2kj, wcol, cb, gw, cwsgw, bidx, ridx, cidx, L,
                     (float4*)out);
  hipLaunchKernelGGL(argmax_scatter, dim3((SS * BB * NSINK) / 4), dim3(256), 0, stream,
                     L, gum, out);
}

// Round 4
// 156.331 us; speedup vs baseline: 1.4133x; 1.4133x over previous
//
#include <hip/hip_runtime.h>
#include <math.h>
#include <stdint.h>

// Problem constants (static per reference)
#define BB 8
#define NN 384
#define FF 64
#define TT 192
#define NSRC 383          // T + TAU - 1
#define NSINK 192
#define SS 5
#define NEDGE 441600      // B * 55200
#define BN (BB * NN)      // 3072
#define TILE_E 128
#define NBLKE (NEDGE / TILE_E)    // 3450 exactly
#define OUTV ((BB * NN * NN) / 4) // 294912 float4 to zero

// ---------------- prep: node projections (row-major) + weight folding ----------------
// blocks 0..BN-1: A[bn][k] = (nodes[bn] @ w1_top)[k] + b1[k];  Bv[bn][k] = (nodes[bn] @ w1_bot)[k]
// block BN: W2kj[k][j] = g1[k]*w2[k][j] (k-major); wcol[j] = sum_k W2kj[k][j]
//           cb[j] = b2[j] + sum_k be1[k]*w2[k][j]
//           gw[j] = g2[j]*w3[j];  cwsgw = {b3 + sum_j be2[j]*w3[j], sum_j gw[j]}
__global__ __launch_bounds__(64) void prep_all(
    const float* __restrict__ nodes, const float* __restrict__ w1,
    const float* __restrict__ b1,
    const float* __restrict__ w2, const float* __restrict__ b2,
    const float* __restrict__ g1, const float* __restrict__ be1,
    const float* __restrict__ g2, const float* __restrict__ be2,
    const float* __restrict__ w3, const float* __restrict__ b3,
    float* __restrict__ A, float* __restrict__ Bv,
    float* __restrict__ W2kj, float* __restrict__ wcol,
    float* __restrict__ cb, float* __restrict__ gw,
    float* __restrict__ cwsgw) {
  const int bn = blockIdx.x;
  if (bn < BN) {
    const int k = threadIdx.x;
    __shared__ float nd[FF];
    nd[k] = nodes[bn * FF + k];
    __syncthreads();
    float a = b1[k];
    float bb = 0.f;
#pragma unroll
    for (int f = 0; f < FF; ++f) {
      a  = fmaf(nd[f], w1[f * FF + k], a);
      bb = fmaf(nd[f], w1[(FF + f) * FF + k], bb);
    }
    A[bn * FF + k] = a;
    Bv[bn * FF + k] = bb;
  } else {
    const int j = threadIdx.x;
    float cbj = b2[j];
    float wc = 0.f;
    for (int k = 0; k < FF; ++k) {
      const float wraw = w2[k * FF + j];
      const float w = g1[k] * wraw;
      W2kj[k * FF + j] = w;
      wc += w;
      cbj = fmaf(be1[k], wraw, cbj);
    }
    wcol[j] = wc;
    cb[j] = cbj;
    const float gwj = g2[j] * w3[j];
    gw[j] = gwj;
    __shared__ float sA[FF], sB[FF];
    sA[j] = gwj;
    sB[j] = be2[j] * w3[j];
    __syncthreads();
    if (j == 0) {
      float a = 0.f, bq = 0.f;
      for (int i = 0; i < FF; ++i) { a += sA[i]; bq += sB[i]; }
      cwsgw[0] = b3[0] + bq;
      cwsgw[1] = a;
    }
  }
}

// ---------------- main: block-tiled LDS GEMM, 128 edges/block ----------------
// threads: 256.  Register tile: 4 edges x 8 j per thread (32 accums).
// thread -> (eg = tid>>3 in [0,32), joct = tid&7 in [0,8))
__global__ __launch_bounds__(256, 4) void edge_mlp(
    const float* __restrict__ A, const float* __restrict__ Bv,
    const float* __restrict__ W2kj, const float* __restrict__ wcolg,
    const float* __restrict__ cbg, const float* __restrict__ gwg,
    const float* __restrict__ cwsgw,
    const int* __restrict__ bidx, const int* __restrict__ ridx,
    const int* __restrict__ cidx, float* __restrict__ L,
    float4* __restrict__ outv) {
  __shared__ float X[FF][TILE_E];    // 32 KB, k-major raw relu(a+b)
  __shared__ float Wl[FF][FF];       // 16 KB, k-major
  __shared__ float St[TILE_E][2];    // 1 KB, {mu, rstd} per edge

  const int tid = threadIdx.x;
  const int gtid = blockIdx.x * 256 + tid;
  if (gtid < OUTV) outv[gtid] = make_float4(0.f, 0.f, 0.f, 0.f);

  const int e0 = blockIdx.x * TILE_E;

  // ---- stage W2 (4096 floats, coalesced float4) ----
  {
    const float4* src = (const float4*)W2kj;
    float4* dst = (float4*)&Wl[0][0];
#pragma unroll
    for (int i = 0; i < 4; ++i) dst[tid + 256 * i] = src[tid + 256 * i];
  }

  // ---- phase 1: build X + per-edge LN stats (2 threads per edge) ----
  {
    const int e = tid >> 1;       // 0..127
    const int kh = tid & 1;       // which 32-k half
    const int ge = e0 + e;
    const int b = bidx[ge], r = ridx[ge], c = cidx[ge];
    const float4* pa = (const float4*)(A + (b * NN + r) * FF + kh * 32);
    const float4* pb = (const float4*)(Bv + (b * NN + c) * FF + kh * 32);
    float s = 0.f, q = 0.f;
#pragma unroll
    for (int i = 0; i < 8; ++i) {
      const float4 av = pa[i];
      const float4 bv = pb[i];
      const float x0 = fmaxf(av.x + bv.x, 0.f);
      const float x1 = fmaxf(av.y + bv.y, 0.f);
      const float x2 = fmaxf(av.z + bv.z, 0.f);
      const float x3 = fmaxf(av.w + bv.w, 0.f);
      const int kb = kh * 32 + 4 * i;
      X[kb + 0][e] = x0; X[kb + 1][e] = x1;
      X[kb + 2][e] = x2; X[kb + 3][e] = x3;
      s += x0; s += x1; s += x2; s += x3;
      q = fmaf(x0, x0, q); q = fmaf(x1, x1, q);
      q = fmaf(x2, x2, q); q = fmaf(x3, x3, q);
    }
    // combine the two halves (lanes 2e, 2e+1 adjacent in-wave)
    s += __shfl_xor(s, 1, 64);
    q += __shfl_xor(q, 1, 64);
    const float mu = s * (1.f / FF);
    const float rstd = 1.f / sqrtf(q * (1.f / FF) - mu * mu + 1e-5f);
    St[e][kh] = kh ? rstd : mu;
  }

  // ---- per-thread j-range constants (tiny tables, L1-hot) ----
  const int joct = tid & 7;
  const int eg = tid >> 3;
  float wc[8], cbv[8], gwv[8];
  *(float4*)&wc[0] = *(const float4*)(wcolg + 8 * joct);
  *(float4*)&wc[4] = *(const float4*)(wcolg + 8 * joct + 4);
  *(float4*)&cbv[0] = *(const float4*)(cbg + 8 * joct);
  *(float4*)&cbv[4] = *(const float4*)(cbg + 8 * joct + 4);
  *(float4*)&gwv[0] = *(const float4*)(gwg + 8 * joct);
  *(float4*)&gwv[4] = *(const float4*)(gwg + 8 * joct + 4);
  const float cw = cwsgw[0], sgw = cwsgw[1];

  __syncthreads();

  // ---- phase 2: k-loop GEMM, 4 edges x 8 j per thread ----
  float t[4][8];
#pragma unroll
  for (int ei = 0; ei < 4; ++ei)
#pragma unroll
    for (int jj = 0; jj < 8; ++jj) t[ei][jj] = 0.f;

#pragma unroll 8
  for (int k = 0; k < FF; ++k) {
    const float4 x4 = *(const float4*)&X[k][4 * eg];
    float w[8];
    *(float4*)&w[0] = *(const float4*)&Wl[k][8 * joct];
    *(float4*)&w[4] = *(const float4*)&Wl[k][8 * joct + 4];
    const float xe[4] = {x4.x, x4.y, x4.z, x4.w};
#pragma unroll
    for (int ei = 0; ei < 4; ++ei)
#pragma unroll
      for (int jj = 0; jj < 8; ++jj)
        t[ei][jj] = fmaf(xe[ei], w[jj], t[ei][jj]);
  }

  // ---- epilogue: LN1-affine + relu + LN2 stats, reduce over joct lanes ----
  float mu_[4], rs_[4];
#pragma unroll
  for (int ei = 0; ei < 4; ++ei) {
    mu_[ei] = St[4 * eg + ei][0];
    rs_[ei] = St[4 * eg + ei][1];
  }
  float s1[4], s2[4], s3[4];
#pragma unroll
  for (int ei = 0; ei < 4; ++ei) { s1[ei] = 0.f; s2[ei] = 0.f; s3[ei] = 0.f; }
#pragma unroll
  for (int ei = 0; ei < 4; ++ei) {
#pragma unroll
    for (int jj = 0; jj < 8; ++jj) {
      const float pre = fmaf(rs_[ei], fmaf(-mu_[ei], wc[jj], t[ei][jj]), cbv[jj]);
      const float tr = fmaxf(pre, 0.f);
      s1[ei] += tr;
      s2[ei] = fmaf(tr, tr, s2[ei]);
      s3[ei] = fmaf(tr, gwv[jj], s3[ei]);
    }
  }
#pragma unroll
  for (int off = 1; off <= 4; off <<= 1) {
#pragma unroll
    for (int ei = 0; ei < 4; ++ei) {
      s1[ei] += __shfl_xor(s1[ei], off, 64);
      s2[ei] += __shfl_xor(s2[ei], off, 64);
      s3[ei] += __shfl_xor(s3[ei], off, 64);
    }
  }
  if (joct < 4) {
    const int ei = joct;
    const int ge = e0 + 4 * eg + ei;
    const int b = bidx[ge], r = ridx[ge], c = cidx[ge];
    const float mu2 = s1[ei] * (1.f / FF);
    const float var2 = s2[ei] * (1.f / FF) - mu2 * mu2;
    const float rstd2 = 1.f / sqrtf(var2 + 1e-5f);
    const float logit = fmaf(rstd2, fmaf(-mu2, sgw, s3[ei]), cw);
    L[(b * NSINK + (r - TT)) * NSRC + c] = logit;
  }
}

// ---------------- argmax over sources + scatter ones ----------------
__global__ __launch_bounds__(256) void argmax_scatter(
    const float* __restrict__ L, const float* __restrict__ gum,
    float* __restrict__ out) {
  const int task = blockIdx.x * 4 + (threadIdx.x >> 6);  // ((s*B+b)*192+row)
  const int lane = threadIdx.x & 63;
  const int row = task % NSINK;
  const int sb = task / NSINK;   // s*B + b
  const int b = sb & 7;
  const int r = row + TT;

  const float* __restrict__ lrow = L + (b * NSINK + row) * NSRC;
  const float* __restrict__ grow = gum + task * NSRC;

  float bv = -INFINITY;
  int bi = 0;
  for (int c = lane; c < r; c += 64) {
    const float v = lrow[c] + grow[c];
    if (v > bv) { bv = v; bi = c; }   // strict > keeps smallest index per lane
  }
#pragma unroll
  for (int off = 32; off > 0; off >>= 1) {
    const float ov = __shfl_xor(bv, off, 64);
    const int oi = __shfl_xor(bi, off, 64);
    if (ov > bv || (ov == bv && oi < bi)) { bv = ov; bi = oi; }
  }
  if (lane == 0) out[(b * NN + r) * NN + bi] = 1.0f;
}

extern "C" void kernel_launch(void* const* d_in, const int* in_sizes, int n_in,
                              void* d_out, int out_size, void* d_ws, size_t ws_size,
                              hipStream_t stream) {
  const float* nodes = (const float*)d_in[0];
  const float* w1 = (const float*)d_in[1];
  const float* b1 = (const float*)d_in[2];
  const float* g1 = (const float*)d_in[3];
  const float* be1 = (const float*)d_in[4];
  const float* w2 = (const float*)d_in[5];
  const float* b2 = (const float*)d_in[6];
  const float* g2 = (const float*)d_in[7];
  const float* be2 = (const float*)d_in[8];
  const float* w3 = (const float*)d_in[9];
  const float* b3 = (const float*)d_in[10];
  const float* gum = (const float*)d_in[11];
  const int* bidx = (const int*)d_in[12];
  const int* ridx = (const int*)d_in[13];
  const int* cidx = (const int*)d_in[14];
  float* out = (float*)d_out;

  // workspace layout (floats)
  float* ws = (float*)d_ws;
  float* A = ws;                       // 8*384*64 = 196608
  float* Bv = A + BN * FF;             // 196608
  float* W2kj = Bv + BN * FF;          // 4096
  float* wcol = W2kj + FF * FF;        // 64
  float* cb = wcol + FF;               // 64
  float* gw = cb + FF;                 // 64
  float* cwsgw = gw + FF;              // 2
  float* L = ws + 397520;              // 8*192*383 = 588288
  (void)ws_size; (void)n_in; (void)in_sizes; (void)out_size;

  hipLaunchKernelGGL(prep_all, dim3(BN + 1), dim3(64), 0, stream,
                     nodes, w1, b1, w2, b2, g1, be1, g2, be2, w3, b3,
                     A, Bv, W2kj, wcol, cb, gw, cwsgw);
  hipLaunchKernelGGL(edge_mlp, dim3(NBLKE), dim3(256), 0, stream,
                     A, Bv, W2kj, wcol, cb, gw, cwsgw, bidx, ridx, cidx, L,
                     (float4*)out);
  hipLaunchKernelGGL(argmax_scatter, dim3((SS * BB * NSINK) / 4), dim3(256), 0, stream,
                     L, gum, out);
}